// Round 24
// baseline (133.587 us; speedup 1.0000x reference)
//
#include <hip/hip_runtime.h>
#include <hip/hip_bf16.h>

typedef unsigned short u16;
typedef __attribute__((ext_vector_type(8))) short short8;
typedef _Float16 half8 __attribute__((ext_vector_type(8)));
typedef __attribute__((ext_vector_type(4))) float f32x4;
typedef __attribute__((ext_vector_type(4))) unsigned int u32x4;

#define CC    128
#define WW    48
#define HW2   2304      // 48*48
#define NHW   46
#define NQ    2116      // 46*46
#define NPIX  2304      // pixels per image
#define DSTRIDE ((size_t)NPIX * NPIX + 64)   // elems per set, +tail pad for vector overrun
#define BATCH 2
#define MT    126       // H rows emitted per tile
#define NTC   190       // H cols emitted per tile
#define DTS   200       // Dt LDS row stride (u16 units)

__device__ __forceinline__ u16 f2bf(float f) {
  union { float f; unsigned u; } x; x.f = f;
  unsigned r = (x.u + 0x7fffu + ((x.u >> 16) & 1u)) >> 16;
  return (u16)r;
}

// ---- kernel 1: per-pixel normalize + transpose to [pix][128c] bf16, chunk-swizzled ----
__global__ __launch_bounds__(256) void k_norm(const float* __restrict__ pred,
                                              const float* __restrict__ targ,
                                              u16* __restrict__ PnT, u16* __restrict__ TnT) {
  const int img = blockIdx.y;          // 0..5 : 0-1 pred, 2-5 target
  const int p0  = blockIdx.x * 64;     // 36 blocks of 64 pixels
  const int tid = threadIdx.x;
  const float* src = img < 2 ? pred + (size_t)img * CC * HW2
                             : targ + (size_t)(img - 2) * CC * HW2;
  u16* out = img < 2 ? PnT + (size_t)img * NPIX * CC
                     : TnT + (size_t)(img - 2) * NPIX * CC;

  __shared__ float sT[64][129];
  __shared__ float sInv[64];

  #pragma unroll
  for (int it = 0; it < 32; ++it) {
    int idx = it * 256 + tid;
    int c = idx >> 6, p = idx & 63;
    sT[p][c] = src[(size_t)c * HW2 + p0 + p];
  }
  __syncthreads();
  if (tid < 64) {
    float s = 0.f;
    for (int c = 0; c < CC; ++c) { float v = sT[tid][c]; s += v * v; }
    sInv[tid] = 1.0f / fmaxf(sqrtf(s), 1e-12f);
  }
  __syncthreads();
  #pragma unroll
  for (int it = 0; it < 4; ++it) {
    int cid = it * 256 + tid;
    int p = cid >> 4, g = cid & 15;
    int r = p0 + p;
    int sc = (g & ~7) | ((g & 7) ^ (r & 7));
    float inv = sInv[p];
    unsigned pack[4];
    #pragma unroll
    for (int e = 0; e < 8; ++e) {
      float v = sT[p][sc * 8 + e] * inv;
      if ((e & 1) == 0) pack[e >> 1] = (unsigned)f2bf(v);
      else              pack[e >> 1] |= ((unsigned)f2bf(v)) << 16;
    }
    u32x4 o; o.x = pack[0]; o.y = pack[1]; o.z = pack[2]; o.w = pack[3];
    *reinterpret_cast<u32x4*>(out + (size_t)r * CC + g * 8) = o;
  }
}

// ---- kernel 2: pixel-dot GEMM (128x192), dual-half upfront staging + counted vmcnt,
//      in-LDS diagonal-3 epilogue -> H (f16) ----
__global__ __launch_bounds__(512, 2) void k_pixdotH(const u16* __restrict__ PnT, const u16* __restrict__ TnT,
                                                    u16* __restrict__ H) {
  __shared__ u16 buf[40960];           // 80 KB
  // per-K-half contiguous regions (global_load_lds dest must be lane-linear):
  u16* sAh[2] = { buf, buf + 8192 };               // each 128 rows x 8 chunks (1024 slots)
  u16* sBh[2] = { buf + 16384, buf + 28672 };      // each 192 rows x 8 chunks (1536 slots)
  const int nt = blockIdx.x, mt = blockIdx.y, s = blockIdx.z;
  const int tid = threadIdx.x, lane = tid & 63, wid = tid >> 6;
  const int wm = wid >> 2, wn = wid & 3;
  const int r15 = lane & 15, g16 = lane >> 4;
  const int m0 = mt * MT, n0 = nt * NTC;

  const u16* Ab = PnT + (size_t)(s >> 1) * NPIX * CC;
  const u16* Bb = TnT + (size_t)s * NPIX * CC;
  u16* Hs = H + (size_t)s * DSTRIDE;

  auto stageA = [&](int h) {           // one K-half of A: 1024 slots, 2/thread, linear dest
    #pragma unroll
    for (int i = 0; i < 2; ++i) {
      int idx = i * 512 + tid;
      int row = idx >> 3, lc = idx & 7;
      int grow = m0 + row; grow = grow < 2303 ? grow : 2303;
      __builtin_amdgcn_global_load_lds(
        (const __attribute__((address_space(1))) unsigned*)(Ab + (size_t)grow * CC + (h * 8 + lc) * 8),
        (__attribute__((address_space(3))) unsigned*)&sAh[h][idx * 8], 16, 0, 0);
    }
  };
  auto stageB = [&](int h) {           // one K-half of B: 1536 slots, 3/thread, linear dest
    #pragma unroll
    for (int i = 0; i < 3; ++i) {
      int idx = i * 512 + tid;
      int row = idx >> 3, lc = idx & 7;
      int grow = n0 + row; grow = grow < 2303 ? grow : 2303;
      __builtin_amdgcn_global_load_lds(
        (const __attribute__((address_space(1))) unsigned*)(Bb + (size_t)grow * CC + (h * 8 + lc) * 8),
        (__attribute__((address_space(3))) unsigned*)&sBh[h][idx * 8], 16, 0, 0);
    }
  };

  f32x4 acc[4][3];
  const f32x4 z4 = {0.f, 0.f, 0.f, 0.f};
  #pragma unroll
  for (int i = 0; i < 4; ++i)
    #pragma unroll
    for (int j = 0; j < 3; ++j) acc[i][j] = z4;

  const int arow0 = wm * 64 + r15;
  const int brow0 = wn * 48 + r15;

  auto mfmaPair = [&](int ks0) {       // two K-steps (one K-half)
    #pragma unroll
    for (int ks = ks0; ks < ks0 + 2; ++ks) {
      const int c = ks * 4 + g16;
      const int h = c >> 3, lc = c & 7;
      short8 af[4], bfv[3];
      #pragma unroll
      for (int mi = 0; mi < 4; ++mi) {
        int row = arow0 + mi * 16;
        int gr = m0 + row;                     // global row drives the un-swizzle
        af[mi] = *reinterpret_cast<const short8*>(
          &sAh[h][row * 64 + ((lc ^ (gr & 7)) * 8)]);
      }
      #pragma unroll
      for (int ni = 0; ni < 3; ++ni) {
        int row = brow0 + ni * 16;
        int gr = n0 + row;
        bfv[ni] = *reinterpret_cast<const short8*>(
          &sBh[h][row * 64 + ((lc ^ (gr & 7)) * 8)]);
      }
      __builtin_amdgcn_s_setprio(1);
      #pragma unroll
      for (int mi = 0; mi < 4; ++mi)
        #pragma unroll
        for (int ni = 0; ni < 3; ++ni)
          acc[mi][ni] = __builtin_amdgcn_mfma_f32_16x16x32_bf16(af[mi], bfv[ni], acc[mi][ni], 0, 0, 0);
      __builtin_amdgcn_s_setprio(0);
    }
  };

  // issue BOTH halves upfront; counted wait lands half-0 while half-1 stays in flight
  stageA(0); stageB(0);                // 5 loads/thread (oldest)
  stageA(1); stageB(1);                // 5 more in flight
  asm volatile("s_waitcnt vmcnt(5)" ::: "memory");   // oldest 5 (half-0) landed
  __builtin_amdgcn_s_barrier();        // half-0 landed for all waves
  mfmaPair(0);                         // K-steps 0,1 (chunks 0..7); h1 flying underneath
  asm volatile("s_waitcnt vmcnt(0)" ::: "memory");
  __builtin_amdgcn_s_barrier();        // half-1 landed
  mfmaPair(2);                         // K-steps 2,3 (chunks 8..15)

  // ---- spill D tile to LDS as f16, aliasing the staging buffers ----
  __syncthreads();                     // all MFMA operand reads done
  u16* Dt = buf;                       // [128][DTS=200]
  #pragma unroll
  for (int mi = 0; mi < 4; ++mi)
    #pragma unroll
    for (int ni = 0; ni < 3; ++ni) {
      int col = wn * 48 + ni * 16 + r15;
      #pragma unroll
      for (int rg = 0; rg < 4; ++rg) {
        int row = wm * 64 + mi * 16 + g16 * 4 + rg;
        Dt[row * DTS + col] = __builtin_bit_cast(u16, (_Float16)acc[mi][ni][rg]);
      }
    }
  __syncthreads();

  // ---- emit H = diagonal-3 of Dt (f16 packed adds), interior 126x190 ----
  for (int t = tid; t < 126 * 24; t += 512) {    // 126 rows x 24 col-chunks
    int rr = t / 24, c8 = t - rr * 24;
    int grow = m0 + rr;
    if (grow >= 2302) continue;
    if ((grow % 48) >= 46) continue;             // rows never read by any tap
    int lcol = c8 * 8;
    int lim = NTC - lcol;
    int glim = 2302 - (n0 + lcol);
    lim = lim < glim ? lim : glim;
    if (lim <= 0) continue;
    int base = rr * DTS + lcol;
    half8 a0 = *reinterpret_cast<const half8*>(&Dt[base]);
    half8 b0 = *reinterpret_cast<const half8*>(&Dt[base + DTS]);
    half8 b1 = *reinterpret_cast<const half8*>(&Dt[base + DTS + 8]);
    half8 c0 = *reinterpret_cast<const half8*>(&Dt[base + 2 * DTS]);
    half8 c1 = *reinterpret_cast<const half8*>(&Dt[base + 2 * DTS + 8]);
    half8 s1v = __builtin_shufflevector(b0, b1, 1, 2, 3, 4, 5, 6, 7, 8);
    half8 s2v = __builtin_shufflevector(c0, c1, 2, 3, 4, 5, 6, 7, 8, 9);
    half8 sum = a0 + s1v + s2v;
    u32x4 pk = __builtin_bit_cast(u32x4, sum);
    u16* dst = Hs + (size_t)grow * NPIX + n0 + lcol;
    int nd = lim >= 8 ? 4 : (lim >> 1);          // lim even by construction
    #pragma unroll
    for (int d = 0; d < 4; ++d)
      if (d < nd) *reinterpret_cast<unsigned*>(dst + 2 * d) = pk[d];
  }
}

// ---- kernel 3: packed-f16 stencil, vertical query pair per block, fused final reduce ----
__global__ __launch_bounds__(512) void k_stencil(const u16* __restrict__ H,
                                                 const float* __restrict__ pred,
                                                 const float* __restrict__ targ,
                                                 float* __restrict__ msep,
                                                 unsigned* __restrict__ cnt,
                                                 float* __restrict__ outp) {
  const int bid = blockIdx.x;
  const int b = bid >= 1058 ? 1 : 0;
  const int j = bid - b * 1058;
  const int xcd = j & 7, pos = j >> 3;
  const int jswz = (xcd < 2 ? xcd * 133 : 266 + (xcd - 2) * 132) + pos;

  const int tid = threadIdx.x;
  const int hid = tid >> 8, htid = tid & 255;    // half (query), index in half
  const int lane = tid & 63, wid = tid >> 6;     // waves 0-3 = half 0, 4-7 = half 1
  const int qyp = jswz / NHW, qx = jswz - qyp * NHW;   // vertical pair (2*qyp, 2*qyp+1)
  const int qy = 2 * qyp + hid;
  const int q = qy * NHW + qx;
  const int qp = qy * WW + qx;

  const _Float16 ninf = __builtin_bit_cast(_Float16, (u16)0xFC00);
  const half8 ninf8 = {ninf, ninf, ninf, ninf, ninf, ninf, ninf, ninf};

  half8 t0[3], t1[3], t2[3];
  int nb[3];
  bool act[3];

  // ---- phase 1a: issue ALL loads before any arithmetic (latency overlap) ----
  #pragma unroll
  for (int it = 0; it < 3; ++it) {
    int t = it * 256 + htid;
    act[it] = t < 552;
    nb[it] = 0;
    if (act[it]) {
      int kc = t / 276; int rem = t - kc * 276;
      int ny = rem / 6, cx = rem - ny * 6;
      const u16* Hs = H + (size_t)(b * 2 + kc) * DSTRIDE;
      int colb = ny * 48 + cx * 8;
      t0[it] = *reinterpret_cast<const half8*>(Hs + (size_t)qp * NPIX + colb);
      t1[it] = *reinterpret_cast<const half8*>(Hs + (size_t)(qp + 48) * NPIX + colb + 48);
      t2[it] = *reinterpret_cast<const half8*>(Hs + (size_t)(qp + 96) * NPIX + colb + 96);
      nb[it] = kc * NQ + ny * NHW + cx * 8;
    }
  }
  // ---- phase 1b: sums + packed max, cache sm in regs for phase 2 ----
  half8 smc[3];
  half8 pmax = ninf8;
  #pragma unroll
  for (int it = 0; it < 3; ++it) {
    smc[it] = ninf8;
    if (act[it]) {
      int t = it * 256 + htid;
      int cx = (t % 276) % 6;
      half8 sm = t0[it] + t1[it] + t2[it];
      if (cx == 5) { sm[6] = ninf; sm[7] = ninf; }   // mask nx=46,47
      smc[it] = sm;
      pmax = __builtin_elementwise_max(pmax, sm);
    }
  }
  float m = (float)pmax[0];
  #pragma unroll
  for (int e = 1; e < 8; ++e) { float v = (float)pmax[e]; m = v > m ? v : m; }
  #pragma unroll
  for (int off = 1; off < 64; off <<= 1) {
    float o = __shfl_xor(m, off, 64);
    m = o > m ? o : m;
  }
  __shared__ float sv[8];
  __shared__ int si[8];
  __shared__ float rsum[8];
  __shared__ bool slast;
  if (lane == 0) sv[wid] = m;
  __syncthreads();
  float M = sv[hid * 4];
  #pragma unroll
  for (int wv = 1; wv < 4; ++wv) { float v = sv[hid * 4 + wv]; M = v > M ? v : M; }

  // ---- phase 2: threads whose max hit M rescan their cached regs ----
  int nmin = 0x7fffffff;
  if (m == M) {
    #pragma unroll
    for (int it = 0; it < 3; ++it) {
      #pragma unroll
      for (int e = 0; e < 8; ++e) {
        float sc = (float)smc[it][e];
        int n = nb[it] + e;
        if (sc == M && n < nmin) nmin = n;
      }
    }
  }
  #pragma unroll
  for (int off = 1; off < 64; off <<= 1) {
    int o = __shfl_xor(nmin, off, 64);
    nmin = o < nmin ? o : nmin;
  }
  if (lane == 0) si[wid] = nmin;
  __syncthreads();
  int fi = si[hid * 4];
  #pragma unroll
  for (int wv = 1; wv < 4; ++wv) { int v = si[hid * 4 + wv]; fi = v < fi ? v : fi; }

  // ---- raw-patch MSE against the selected target patch ----
  int nkc = fi >= NQ ? 1 : 0;
  int ns = fi - nkc * NQ;
  ns = ns < NQ ? ns : NQ - 1;
  int ny = ns / NHW, nx = ns - ny * NHW;
  const float* P = pred + (size_t)b * CC * HW2;
  const float* T = targ + (size_t)(b * 2 + nkc) * CC * HW2;
  float ssum = 0.f;
  for (int i = htid; i < CC * 9; i += 256) {
    int c = i / 9, sp = i - 9 * c;
    int di = sp / 3, dj = sp - 3 * di;
    float d = P[(size_t)c * HW2 + (qy + di) * WW + qx + dj]
            - T[(size_t)c * HW2 + (ny + di) * WW + nx + dj];
    ssum += d * d;
  }
  #pragma unroll
  for (int off = 1; off < 64; off <<= 1) ssum += __shfl_xor(ssum, off, 64);
  if (lane == 0) rsum[wid] = ssum;
  __syncthreads();
  if (htid == 0) {
    float t = 0.f;
    #pragma unroll
    for (int wv = 0; wv < 4; ++wv) t += rsum[hid * 4 + wv];
    msep[b * NQ + q] = t;
  }

  // ---- deterministic last-block final reduction (fused k_final) ----
  __syncthreads();
  if (tid == 0) {
    __threadfence();                              // msep writes visible device-wide
    unsigned v = atomicAdd(cnt, 1u);
    slast = (v == 2 * 1058 - 1);
  }
  __syncthreads();
  if (slast) {
    __threadfence();                              // acquire: see all msep writes
    float s = 0.f;
    for (int i = tid; i < BATCH * NQ; i += 512) s += msep[i];
    __shared__ float red[512];
    red[tid] = s; __syncthreads();
    for (int st = 256; st > 0; st >>= 1) { if (tid < st) red[tid] += red[tid + st]; __syncthreads(); }
    if (tid == 0) outp[0] = red[0] * (1.0f / 4875264.0f);   // 2*2116*128*9
  }
}

extern "C" void kernel_launch(void* const* d_in, const int* in_sizes, int n_in,
                              void* d_out, int out_size, void* d_ws, size_t ws_size,
                              hipStream_t stream) {
  const float* pred = (const float*)d_in[0];
  const float* targ = (const float*)d_in[1];
  char* ws = (char*)d_ws;

  size_t offP = 0;
  size_t offT = offP + (size_t)2 * NPIX * CC * 2;     // PnT: 1,179,648
  size_t offH = offT + (size_t)4 * NPIX * CC * 2;     // TnT: 2,359,296
  size_t offM = offH + (size_t)4 * DSTRIDE * 2;       // H (4 sets): 42,467,840
  size_t offC = offM + (size_t)BATCH * NQ * 4;        // msep: 16,928

  u16*      PnT  = (u16*)(ws + offP);
  u16*      TnT  = (u16*)(ws + offT);
  u16*      Hbuf = (u16*)(ws + offH);
  float*    msep = (float*)(ws + offM);
  unsigned* cnt  = (unsigned*)(ws + offC);            // total ~46 MB

  hipMemsetAsync(cnt, 0, 4, stream);
  k_norm<<<dim3(36, 6), 256, 0, stream>>>(pred, targ, PnT, TnT);
  k_pixdotH<<<dim3(13, 19, 4), 512, 0, stream>>>(PnT, TnT, Hbuf);
  k_stencil<<<dim3(2 * 1058), 512, 0, stream>>>(Hbuf, pred, targ, msep, cnt, (float*)d_out);
}

// Round 25
// 65.182 us; speedup vs baseline: 2.0494x; 2.0494x over previous
//
#include <hip/hip_runtime.h>
#include <hip/hip_bf16.h>

typedef unsigned short u16;
typedef __attribute__((ext_vector_type(8))) short short8;
typedef _Float16 half8 __attribute__((ext_vector_type(8)));
typedef __attribute__((ext_vector_type(4))) float f32x4;
typedef __attribute__((ext_vector_type(4))) unsigned int u32x4;

#define CC    128
#define WW    48
#define HW2   2304      // 48*48
#define NHW   46
#define NQ    2116      // 46*46
#define NPIX  2304      // pixels per image
#define DSTRIDE ((size_t)NPIX * NPIX + 64)   // elems per set, +tail pad for vector overrun
#define BATCH 2
#define MT    126       // H rows emitted per tile
#define NTC   190       // H cols emitted per tile
#define DTS   200       // Dt LDS row stride (u16 units)

__device__ __forceinline__ u16 f2bf(float f) {
  union { float f; unsigned u; } x; x.f = f;
  unsigned r = (x.u + 0x7fffu + ((x.u >> 16) & 1u)) >> 16;
  return (u16)r;
}

// ---- kernel 1: per-pixel normalize + transpose to [pix][128c] bf16, chunk-swizzled ----
__global__ __launch_bounds__(256) void k_norm(const float* __restrict__ pred,
                                              const float* __restrict__ targ,
                                              u16* __restrict__ PnT, u16* __restrict__ TnT) {
  const int img = blockIdx.y;          // 0..5 : 0-1 pred, 2-5 target
  const int p0  = blockIdx.x * 64;     // 36 blocks of 64 pixels
  const int tid = threadIdx.x;
  const float* src = img < 2 ? pred + (size_t)img * CC * HW2
                             : targ + (size_t)(img - 2) * CC * HW2;
  u16* out = img < 2 ? PnT + (size_t)img * NPIX * CC
                     : TnT + (size_t)(img - 2) * NPIX * CC;

  __shared__ float sT[64][129];
  __shared__ float sInv[64];

  #pragma unroll
  for (int it = 0; it < 32; ++it) {
    int idx = it * 256 + tid;
    int c = idx >> 6, p = idx & 63;
    sT[p][c] = src[(size_t)c * HW2 + p0 + p];
  }
  __syncthreads();
  if (tid < 64) {
    float s = 0.f;
    for (int c = 0; c < CC; ++c) { float v = sT[tid][c]; s += v * v; }
    sInv[tid] = 1.0f / fmaxf(sqrtf(s), 1e-12f);
  }
  __syncthreads();
  #pragma unroll
  for (int it = 0; it < 4; ++it) {
    int cid = it * 256 + tid;
    int p = cid >> 4, g = cid & 15;
    int r = p0 + p;
    int sc = (g & ~7) | ((g & 7) ^ (r & 7));
    float inv = sInv[p];
    unsigned pack[4];
    #pragma unroll
    for (int e = 0; e < 8; ++e) {
      float v = sT[p][sc * 8 + e] * inv;
      if ((e & 1) == 0) pack[e >> 1] = (unsigned)f2bf(v);
      else              pack[e >> 1] |= ((unsigned)f2bf(v)) << 16;
    }
    u32x4 o; o.x = pack[0]; o.y = pack[1]; o.z = pack[2]; o.w = pack[3];
    *reinterpret_cast<u32x4*>(out + (size_t)r * CC + g * 8) = o;
  }
}

// ---- kernel 2: pixel-dot GEMM (128x192), dual-half upfront staging + counted vmcnt,
//      in-LDS diagonal-3 epilogue -> H (f16) ----
__global__ __launch_bounds__(512, 2) void k_pixdotH(const u16* __restrict__ PnT, const u16* __restrict__ TnT,
                                                    u16* __restrict__ H) {
  __shared__ u16 buf[40960];           // 80 KB
  // per-K-half contiguous regions (global_load_lds dest must be lane-linear):
  u16* sAh[2] = { buf, buf + 8192 };               // each 128 rows x 8 chunks (1024 slots)
  u16* sBh[2] = { buf + 16384, buf + 28672 };      // each 192 rows x 8 chunks (1536 slots)
  const int nt = blockIdx.x, mt = blockIdx.y, s = blockIdx.z;
  const int tid = threadIdx.x, lane = tid & 63, wid = tid >> 6;
  const int wm = wid >> 2, wn = wid & 3;
  const int r15 = lane & 15, g16 = lane >> 4;
  const int m0 = mt * MT, n0 = nt * NTC;

  const u16* Ab = PnT + (size_t)(s >> 1) * NPIX * CC;
  const u16* Bb = TnT + (size_t)s * NPIX * CC;
  u16* Hs = H + (size_t)s * DSTRIDE;

  auto stageA = [&](int h) {           // one K-half of A: 1024 slots, 2/thread, linear dest
    #pragma unroll
    for (int i = 0; i < 2; ++i) {
      int idx = i * 512 + tid;
      int row = idx >> 3, lc = idx & 7;
      int grow = m0 + row; grow = grow < 2303 ? grow : 2303;
      __builtin_amdgcn_global_load_lds(
        (const __attribute__((address_space(1))) unsigned*)(Ab + (size_t)grow * CC + (h * 8 + lc) * 8),
        (__attribute__((address_space(3))) unsigned*)&sAh[h][idx * 8], 16, 0, 0);
    }
  };
  auto stageB = [&](int h) {           // one K-half of B: 1536 slots, 3/thread, linear dest
    #pragma unroll
    for (int i = 0; i < 3; ++i) {
      int idx = i * 512 + tid;
      int row = idx >> 3, lc = idx & 7;
      int grow = n0 + row; grow = grow < 2303 ? grow : 2303;
      __builtin_amdgcn_global_load_lds(
        (const __attribute__((address_space(1))) unsigned*)(Bb + (size_t)grow * CC + (h * 8 + lc) * 8),
        (__attribute__((address_space(3))) unsigned*)&sBh[h][idx * 8], 16, 0, 0);
    }
  };

  f32x4 acc[4][3];
  const f32x4 z4 = {0.f, 0.f, 0.f, 0.f};
  #pragma unroll
  for (int i = 0; i < 4; ++i)
    #pragma unroll
    for (int j = 0; j < 3; ++j) acc[i][j] = z4;

  const int arow0 = wm * 64 + r15;
  const int brow0 = wn * 48 + r15;

  auto mfmaPair = [&](int ks0) {       // two K-steps (one K-half)
    #pragma unroll
    for (int ks = ks0; ks < ks0 + 2; ++ks) {
      const int c = ks * 4 + g16;
      const int h = c >> 3, lc = c & 7;
      short8 af[4], bfv[3];
      #pragma unroll
      for (int mi = 0; mi < 4; ++mi) {
        int row = arow0 + mi * 16;
        int gr = m0 + row;                     // global row drives the un-swizzle
        af[mi] = *reinterpret_cast<const short8*>(
          &sAh[h][row * 64 + ((lc ^ (gr & 7)) * 8)]);
      }
      #pragma unroll
      for (int ni = 0; ni < 3; ++ni) {
        int row = brow0 + ni * 16;
        int gr = n0 + row;
        bfv[ni] = *reinterpret_cast<const short8*>(
          &sBh[h][row * 64 + ((lc ^ (gr & 7)) * 8)]);
      }
      __builtin_amdgcn_s_setprio(1);
      #pragma unroll
      for (int mi = 0; mi < 4; ++mi)
        #pragma unroll
        for (int ni = 0; ni < 3; ++ni)
          acc[mi][ni] = __builtin_amdgcn_mfma_f32_16x16x32_bf16(af[mi], bfv[ni], acc[mi][ni], 0, 0, 0);
      __builtin_amdgcn_s_setprio(0);
    }
  };

  // issue BOTH halves upfront; counted wait lands half-0 while half-1 stays in flight
  stageA(0); stageB(0);                // 5 loads/thread (oldest)
  stageA(1); stageB(1);                // 5 more in flight
  asm volatile("s_waitcnt vmcnt(5)" ::: "memory");   // oldest 5 (half-0) landed
  __builtin_amdgcn_s_barrier();        // half-0 landed for all waves
  mfmaPair(0);                         // K-steps 0,1 (chunks 0..7); h1 flying underneath
  asm volatile("s_waitcnt vmcnt(0)" ::: "memory");
  __builtin_amdgcn_s_barrier();        // half-1 landed
  mfmaPair(2);                         // K-steps 2,3 (chunks 8..15)

  // ---- spill D tile to LDS as f16, aliasing the staging buffers ----
  __syncthreads();                     // all MFMA operand reads done
  u16* Dt = buf;                       // [128][DTS=200]
  #pragma unroll
  for (int mi = 0; mi < 4; ++mi)
    #pragma unroll
    for (int ni = 0; ni < 3; ++ni) {
      int col = wn * 48 + ni * 16 + r15;
      #pragma unroll
      for (int rg = 0; rg < 4; ++rg) {
        int row = wm * 64 + mi * 16 + g16 * 4 + rg;
        Dt[row * DTS + col] = __builtin_bit_cast(u16, (_Float16)acc[mi][ni][rg]);
      }
    }
  __syncthreads();

  // ---- emit H = diagonal-3 of Dt (f16 packed adds), interior 126x190 ----
  for (int t = tid; t < 126 * 24; t += 512) {    // 126 rows x 24 col-chunks
    int rr = t / 24, c8 = t - rr * 24;
    int grow = m0 + rr;
    if (grow >= 2302) continue;
    if ((grow % 48) >= 46) continue;             // rows never read by any tap
    int lcol = c8 * 8;
    int lim = NTC - lcol;
    int glim = 2302 - (n0 + lcol);
    lim = lim < glim ? lim : glim;
    if (lim <= 0) continue;
    int base = rr * DTS + lcol;
    half8 a0 = *reinterpret_cast<const half8*>(&Dt[base]);
    half8 b0 = *reinterpret_cast<const half8*>(&Dt[base + DTS]);
    half8 b1 = *reinterpret_cast<const half8*>(&Dt[base + DTS + 8]);
    half8 c0 = *reinterpret_cast<const half8*>(&Dt[base + 2 * DTS]);
    half8 c1 = *reinterpret_cast<const half8*>(&Dt[base + 2 * DTS + 8]);
    half8 s1v = __builtin_shufflevector(b0, b1, 1, 2, 3, 4, 5, 6, 7, 8);
    half8 s2v = __builtin_shufflevector(c0, c1, 2, 3, 4, 5, 6, 7, 8, 9);
    half8 sum = a0 + s1v + s2v;
    u32x4 pk = __builtin_bit_cast(u32x4, sum);
    u16* dst = Hs + (size_t)grow * NPIX + n0 + lcol;
    int nd = lim >= 8 ? 4 : (lim >> 1);          // lim even by construction
    #pragma unroll
    for (int d = 0; d < 4; ++d)
      if (d < nd) *reinterpret_cast<unsigned*>(dst + 2 * d) = pk[d];
  }
}

// ---- kernel 3: packed-f16 stencil, VERTICAL query pair per block (qy, qy+1 @ same qx) ----
__global__ __launch_bounds__(512) void k_stencil(const u16* __restrict__ H,
                                                 const float* __restrict__ pred,
                                                 const float* __restrict__ targ,
                                                 float* __restrict__ msep) {
  const int bid = blockIdx.x;
  const int b = bid >= 1058 ? 1 : 0;
  const int j = bid - b * 1058;
  const int xcd = j & 7, pos = j >> 3;
  const int jswz = (xcd < 2 ? xcd * 133 : 266 + (xcd - 2) * 132) + pos;

  const int tid = threadIdx.x;
  const int hid = tid >> 8, htid = tid & 255;    // half (query), index in half
  const int lane = tid & 63, wid = tid >> 6;     // waves 0-3 = half 0, 4-7 = half 1
  const int qyp = jswz / NHW, qx = jswz - qyp * NHW;   // vertical pair (2*qyp, 2*qyp+1)
  const int qy = 2 * qyp + hid;
  const int q = qy * NHW + qx;
  const int qp = qy * WW + qx;

  const _Float16 ninf = __builtin_bit_cast(_Float16, (u16)0xFC00);
  const half8 ninf8 = {ninf, ninf, ninf, ninf, ninf, ninf, ninf, ninf};

  half8 t0[3], t1[3], t2[3];
  int nb[3];
  bool act[3];

  // ---- phase 1a: issue ALL loads before any arithmetic (latency overlap) ----
  #pragma unroll
  for (int it = 0; it < 3; ++it) {
    int t = it * 256 + htid;
    act[it] = t < 552;
    nb[it] = 0;
    if (act[it]) {
      int kc = t / 276; int rem = t - kc * 276;
      int ny = rem / 6, cx = rem - ny * 6;
      const u16* Hs = H + (size_t)(b * 2 + kc) * DSTRIDE;
      int colb = ny * 48 + cx * 8;
      t0[it] = *reinterpret_cast<const half8*>(Hs + (size_t)qp * NPIX + colb);
      t1[it] = *reinterpret_cast<const half8*>(Hs + (size_t)(qp + 48) * NPIX + colb + 48);
      t2[it] = *reinterpret_cast<const half8*>(Hs + (size_t)(qp + 96) * NPIX + colb + 96);
      nb[it] = kc * NQ + ny * NHW + cx * 8;
    }
  }
  // ---- phase 1b: sums + packed max, cache sm in regs for phase 2 ----
  half8 smc[3];
  half8 pmax = ninf8;
  #pragma unroll
  for (int it = 0; it < 3; ++it) {
    smc[it] = ninf8;
    if (act[it]) {
      int t = it * 256 + htid;
      int cx = (t % 276) % 6;
      half8 sm = t0[it] + t1[it] + t2[it];
      if (cx == 5) { sm[6] = ninf; sm[7] = ninf; }   // mask nx=46,47
      smc[it] = sm;
      pmax = __builtin_elementwise_max(pmax, sm);
    }
  }
  float m = (float)pmax[0];
  #pragma unroll
  for (int e = 1; e < 8; ++e) { float v = (float)pmax[e]; m = v > m ? v : m; }
  #pragma unroll
  for (int off = 1; off < 64; off <<= 1) {
    float o = __shfl_xor(m, off, 64);
    m = o > m ? o : m;
  }
  __shared__ float sv[8];
  __shared__ int si[8];
  __shared__ float rsum[8];
  if (lane == 0) sv[wid] = m;
  __syncthreads();
  float M = sv[hid * 4];
  #pragma unroll
  for (int wv = 1; wv < 4; ++wv) { float v = sv[hid * 4 + wv]; M = v > M ? v : M; }

  // ---- phase 2: threads whose max hit M rescan their cached regs ----
  int nmin = 0x7fffffff;
  if (m == M) {
    #pragma unroll
    for (int it = 0; it < 3; ++it) {
      #pragma unroll
      for (int e = 0; e < 8; ++e) {
        float sc = (float)smc[it][e];
        int n = nb[it] + e;
        if (sc == M && n < nmin) nmin = n;
      }
    }
  }
  #pragma unroll
  for (int off = 1; off < 64; off <<= 1) {
    int o = __shfl_xor(nmin, off, 64);
    nmin = o < nmin ? o : nmin;
  }
  if (lane == 0) si[wid] = nmin;
  __syncthreads();
  int fi = si[hid * 4];
  #pragma unroll
  for (int wv = 1; wv < 4; ++wv) { int v = si[hid * 4 + wv]; fi = v < fi ? v : fi; }

  // ---- raw-patch MSE against the selected target patch ----
  int nkc = fi >= NQ ? 1 : 0;
  int ns = fi - nkc * NQ;
  ns = ns < NQ ? ns : NQ - 1;
  int ny = ns / NHW, nx = ns - ny * NHW;
  const float* P = pred + (size_t)b * CC * HW2;
  const float* T = targ + (size_t)(b * 2 + nkc) * CC * HW2;
  float ssum = 0.f;
  for (int i = htid; i < CC * 9; i += 256) {
    int c = i / 9, sp = i - 9 * c;
    int di = sp / 3, dj = sp - 3 * di;
    float d = P[(size_t)c * HW2 + (qy + di) * WW + qx + dj]
            - T[(size_t)c * HW2 + (ny + di) * WW + nx + dj];
    ssum += d * d;
  }
  #pragma unroll
  for (int off = 1; off < 64; off <<= 1) ssum += __shfl_xor(ssum, off, 64);
  if (lane == 0) rsum[wid] = ssum;
  __syncthreads();
  if (htid == 0) {
    float t = 0.f;
    #pragma unroll
    for (int wv = 0; wv < 4; ++wv) t += rsum[hid * 4 + wv];
    msep[b * NQ + q] = t;
  }
}

// ---- kernel 4: final deterministic reduction ----
__global__ void k_final(const float* __restrict__ msep, float* __restrict__ out) {
  int t = threadIdx.x;
  float s = 0.f;
  for (int i = t; i < BATCH * NQ; i += 256) s += msep[i];
  __shared__ float red[256];
  red[t] = s; __syncthreads();
  for (int st = 128; st > 0; st >>= 1) { if (t < st) red[t] += red[t + st]; __syncthreads(); }
  if (t == 0) out[0] = red[0] * (1.0f / 4875264.0f);   // 2*2116*128*9
}

extern "C" void kernel_launch(void* const* d_in, const int* in_sizes, int n_in,
                              void* d_out, int out_size, void* d_ws, size_t ws_size,
                              hipStream_t stream) {
  const float* pred = (const float*)d_in[0];
  const float* targ = (const float*)d_in[1];
  char* ws = (char*)d_ws;

  size_t offP = 0;
  size_t offT = offP + (size_t)2 * NPIX * CC * 2;     // PnT: 1,179,648
  size_t offH = offT + (size_t)4 * NPIX * CC * 2;     // TnT: 2,359,296
  size_t offM = offH + (size_t)4 * DSTRIDE * 2;       // H (4 sets): 42,467,840

  u16*   PnT  = (u16*)(ws + offP);
  u16*   TnT  = (u16*)(ws + offT);
  u16*   Hbuf = (u16*)(ws + offH);
  float* msep = (float*)(ws + offM);                  // total ~46 MB

  k_norm<<<dim3(36, 6), 256, 0, stream>>>(pred, targ, PnT, TnT);
  k_pixdotH<<<dim3(13, 19, 4), 512, 0, stream>>>(PnT, TnT, Hbuf);
  k_stencil<<<dim3(2 * 1058), 512, 0, stream>>>(Hbuf, pred, targ, msep);
  k_final<<<1, 256, 0, stream>>>(msep, (float*)d_out);
}